// Round 1
// baseline (597.126 us; speedup 1.0000x reference)
//
#include <hip/hip_runtime.h>

#define N_NODES 100000
#define N_EDGES 600000
#define N_GRAPHS 64

// ---------------- CSR build ----------------

__global__ void k_count(const int* __restrict__ dst, int* __restrict__ deg) {
    int e = blockIdx.x * 256 + threadIdx.x;
    if (e < N_EDGES) atomicAdd(&deg[dst[e]], 1);
}

// block scans 1024 elements (256 threads x 4)
__global__ void k_scan1(const int* __restrict__ deg, int* __restrict__ offs,
                        int* __restrict__ bsums) {
    __shared__ int s[256];
    int t = threadIdx.x, b = blockIdx.x;
    int base = b * 1024 + t * 4;
    int v0 = (base + 0 < N_NODES) ? deg[base + 0] : 0;
    int v1 = (base + 1 < N_NODES) ? deg[base + 1] : 0;
    int v2 = (base + 2 < N_NODES) ? deg[base + 2] : 0;
    int v3 = (base + 3 < N_NODES) ? deg[base + 3] : 0;
    int tsum = v0 + v1 + v2 + v3;
    s[t] = tsum;
    __syncthreads();
    for (int o = 1; o < 256; o <<= 1) {
        int x = (t >= o) ? s[t - o] : 0;
        __syncthreads();
        s[t] += x;
        __syncthreads();
    }
    int p = s[t] - tsum;  // exclusive prefix within block
    if (base + 0 < N_NODES) offs[base + 0] = p;
    p += v0;
    if (base + 1 < N_NODES) offs[base + 1] = p;
    p += v1;
    if (base + 2 < N_NODES) offs[base + 2] = p;
    p += v2;
    if (base + 3 < N_NODES) offs[base + 3] = p;
    if (t == 255) bsums[b] = s[255];
}

__global__ void k_scan2(const int* __restrict__ bsums, int* __restrict__ boff) {
    __shared__ int s[128];
    int t = threadIdx.x;
    int nb = (N_NODES + 1023) / 1024;  // 98
    int v = (t < nb) ? bsums[t] : 0;
    s[t] = v;
    __syncthreads();
    for (int o = 1; o < 128; o <<= 1) {
        int x = (t >= o) ? s[t - o] : 0;
        __syncthreads();
        s[t] += x;
        __syncthreads();
    }
    boff[t] = s[t] - v;  // exclusive
}

__global__ void k_scan3(int* __restrict__ offs, const int* __restrict__ boff,
                        int* __restrict__ cursor) {
    int i = blockIdx.x * 256 + threadIdx.x;
    if (i < N_NODES) {
        int v = offs[i] + boff[i >> 10];
        offs[i] = v;
        cursor[i] = v;
    }
}

__global__ void k_fill(const int* __restrict__ src, const int* __restrict__ dst,
                       int* __restrict__ cursor, int* __restrict__ ssrc) {
    int e = blockIdx.x * 256 + threadIdx.x;
    if (e < N_EDGES) {
        int d = dst[e];
        int pos = atomicAdd(&cursor[d], 1);
        ssrc[pos] = src[e];
    }
}

// ---------------- SAGE layer 1 (fused aggregate + transform + relu) ----------------
// out[n][d] = relu(b1[d] + sum_k W1l[d][k]*mean[k] + W1r[d][k]*x[n][k]), d<64, k<128

__launch_bounds__(256, 2)
__global__ void k_layer1(const float* __restrict__ x, const int* __restrict__ ssrc,
                         const int* __restrict__ offs, const int* __restrict__ deg,
                         const float* __restrict__ W1l, const float* __restrict__ W1r,
                         const float* __restrict__ b1, float* __restrict__ h1) {
    __shared__ float2 Wc[128 * 64];     // (W1l[d][k], W1r[d][k]) at [k*64+d] : 64 KB
    __shared__ float2 S[4][4][128];     // per wave: 4 nodes x (mean[k], x[k]) : 16 KB
    int tid = threadIdx.x;
    for (int i = tid; i < 128 * 64; i += 256) {
        int k = i >> 6, d = i & 63;
        Wc[i] = make_float2(W1l[d * 128 + k], W1r[d * 128 + k]);
    }
    __syncthreads();

    int wave = tid >> 6, lane = tid & 63;
    float bias = b1[lane];
    int gw = blockIdx.x * 4 + wave;
    int nw = gridDim.x * 4;
    const float2* x2 = (const float2*)x;

    for (int base = gw * 4; base < N_NODES; base += nw * 4) {
        int cnt = min(4, N_NODES - base);
        for (int j = 0; j < cnt; ++j) {
            int node = base + j;
            int o = offs[node], dg = deg[node];
            float ax = 0.f, ay = 0.f;
            for (int t = 0; t < dg; t += 64) {
                int m = min(64, dg - t);
                int idx = (lane < m) ? ssrc[o + t + lane] : 0;
                for (int u = 0; u < m; ++u) {
                    int nb = __shfl(idx, u);
                    float2 v = x2[nb * 64 + lane];
                    ax += v.x;
                    ay += v.y;
                }
            }
            float inv = 1.f / (float)max(dg, 1);
            float2 xi = x2[node * 64 + lane];
            S[wave][j][2 * lane]     = make_float2(ax * inv, xi.x);
            S[wave][j][2 * lane + 1] = make_float2(ay * inv, xi.y);
        }
        float a0 = bias, a1 = bias, a2 = bias, a3 = bias;
#pragma unroll 4
        for (int k = 0; k < 128; ++k) {
            float2 w = Wc[k * 64 + lane];
            float2 s0 = S[wave][0][k]; a0 += w.x * s0.x + w.y * s0.y;
            float2 s1 = S[wave][1][k]; a1 += w.x * s1.x + w.y * s1.y;
            float2 s2 = S[wave][2][k]; a2 += w.x * s2.x + w.y * s2.y;
            float2 s3 = S[wave][3][k]; a3 += w.x * s3.x + w.y * s3.y;
        }
        a0 = fmaxf(a0, 0.f); a1 = fmaxf(a1, 0.f);
        a2 = fmaxf(a2, 0.f); a3 = fmaxf(a3, 0.f);
        if (0 < cnt) h1[(base + 0) * 64 + lane] = a0;
        if (1 < cnt) h1[(base + 1) * 64 + lane] = a1;
        if (2 < cnt) h1[(base + 2) * 64 + lane] = a2;
        if (3 < cnt) h1[(base + 3) * 64 + lane] = a3;
    }
}

// ---------------- SAGE layer 2 (fused aggregate + transform + graph pooling) ----------------
// h2[n][d] = b2[d] + sum_k W2l[d][k]*mean_h1[k] + W2r[d][k]*h1[n][k], d<16, k<64
// pooled per graph via LDS bins (batch_ids sorted -> few graphs per contiguous chunk)

__launch_bounds__(256)
__global__ void k_layer2(const float* __restrict__ h1, const int* __restrict__ ssrc,
                         const int* __restrict__ offs, const int* __restrict__ deg,
                         const int* __restrict__ batch,
                         const float* __restrict__ W2l, const float* __restrict__ W2r,
                         const float* __restrict__ b2,
                         float* __restrict__ gsum, float* __restrict__ gcnt) {
    __shared__ float2 Wc[64 * 16];      // (W2l[d][k], W2r[d][k]) at [k*16+d] : 8 KB
    __shared__ float2 S[4][4][64];      // per wave: 4 nodes x (mean[k], h1[k]) : 8 KB
    __shared__ float bins[N_GRAPHS][17];  // [g][0..15]=sum dims, [g][16]=count
    int tid = threadIdx.x;
    for (int i = tid; i < 64 * 16; i += 256) {
        int k = i >> 4, d = i & 15;
        Wc[i] = make_float2(W2l[d * 64 + k], W2r[d * 64 + k]);
    }
    for (int i = tid; i < N_GRAPHS * 17; i += 256) ((float*)bins)[i] = 0.f;
    __syncthreads();

    int wave = tid >> 6, lane = tid & 63;
    int d = lane & 15, jq = lane >> 4;
    float bias = b2[d];

    int chunk = (N_NODES + gridDim.x - 1) / gridDim.x;
    int cs = blockIdx.x * chunk;
    int ce = min(N_NODES, cs + chunk);

    for (int base = cs + wave * 4; base < ce; base += 16) {
        int cnt = min(4, ce - base);
        for (int j = 0; j < cnt; ++j) {
            int node = base + j;
            int o = offs[node], dg = deg[node];
            float acc = 0.f;
            for (int t = 0; t < dg; t += 64) {
                int m = min(64, dg - t);
                int idx = (lane < m) ? ssrc[o + t + lane] : 0;
                for (int u = 0; u < m; ++u) {
                    int nb = __shfl(idx, u);
                    acc += h1[nb * 64 + lane];
                }
            }
            float inv = 1.f / (float)max(dg, 1);
            S[wave][j][lane] = make_float2(acc * inv, h1[node * 64 + lane]);
        }
        float a = bias;
#pragma unroll 4
        for (int k = 0; k < 64; ++k) {
            float2 w = Wc[k * 16 + d];
            float2 s = S[wave][jq][k];
            a += w.x * s.x + w.y * s.y;
        }
        if (jq < cnt) {
            int node = base + jq;
            int g = batch[node];
            atomicAdd(&bins[g][d], a);
            if (d == 0) atomicAdd(&bins[g][16], 1.f);
        }
    }
    __syncthreads();
    for (int i = tid; i < N_GRAPHS * 17; i += 256) {
        int g = i / 17, c = i - g * 17;
        float v = bins[g][c];
        if (v != 0.f) {
            if (c < 16) atomicAdd(&gsum[g * 16 + c], v);
            else        atomicAdd(&gcnt[g], v);
        }
    }
}

// ---------------- final: BERT head + graph head, concat ----------------

__global__ void k_final(const float* __restrict__ bert, const float* __restrict__ Wad,
                        const float* __restrict__ bad, const float* __restrict__ Wm,
                        const float* __restrict__ bm, const float* __restrict__ gsum,
                        const float* __restrict__ gcnt, float* __restrict__ out) {
    int g = blockIdx.x;
    int t = threadIdx.x;
    if (t < 64) {
        const float4* br = (const float4*)(bert + g * 768);
        const float4* wr = (const float4*)(Wad + t * 768);
        float acc = bad[t];
#pragma unroll 8
        for (int k = 0; k < 192; ++k) {
            float4 bv = br[k], wv = wr[k];
            acc += bv.x * wv.x + bv.y * wv.y + bv.z * wv.z + bv.w * wv.w;
        }
        out[g * 80 + t] = acc;
    } else if (t < 80) {
        int j = t - 64;
        float ic = 1.f / fmaxf(gcnt[g], 1.f);
        float acc = bm[j];
#pragma unroll
        for (int k = 0; k < 16; ++k) acc += Wm[j * 16 + k] * gsum[g * 16 + k] * ic;
        out[g * 80 + t] = acc;
    }
}

extern "C" void kernel_launch(void* const* d_in, const int* in_sizes, int n_in,
                              void* d_out, int out_size, void* d_ws, size_t ws_size,
                              hipStream_t stream) {
    const float* bert   = (const float*)d_in[0];
    const float* node_x = (const float*)d_in[1];
    const int*   edge   = (const int*)d_in[2];
    const int*   batch  = (const int*)d_in[3];
    const float* Wad    = (const float*)d_in[4];
    const float* bad    = (const float*)d_in[5];
    const float* W1l    = (const float*)d_in[6];
    const float* W1r    = (const float*)d_in[7];
    const float* b1     = (const float*)d_in[8];
    const float* W2l    = (const float*)d_in[9];
    const float* W2r    = (const float*)d_in[10];
    const float* b2     = (const float*)d_in[11];
    const float* Wm     = (const float*)d_in[12];
    const float* bm     = (const float*)d_in[13];
    float* out = (float*)d_out;

    const int* src = edge;
    const int* dst = edge + N_EDGES;

    char* ws = (char*)d_ws;
    int*   deg    = (int*)(ws);                     //   400,000 B
    int*   offs   = (int*)(ws + 400000);            //   400,000 B
    int*   cursor = (int*)(ws + 800000);            //   400,000 B
    int*   bsums  = (int*)(ws + 1200000);           //       512 B
    int*   boff   = (int*)(ws + 1200512);           //       512 B
    int*   ssrc   = (int*)(ws + 1201024);           // 2,400,000 B
    float* h1     = (float*)(ws + 3601024);         // 25,600,000 B
    float* gsum   = (float*)(ws + 29201024);        //     4,096 B
    float* gcnt   = (float*)(ws + 29205120);        //       256 B
    // total ~29.2 MB

    hipMemsetAsync(deg, 0, 400000, stream);
    hipMemsetAsync(gsum, 0, 4096 + 256, stream);  // gsum + gcnt contiguous

    k_count<<<(N_EDGES + 255) / 256, 256, 0, stream>>>(dst, deg);
    k_scan1<<<(N_NODES + 1023) / 1024, 256, 0, stream>>>(deg, offs, bsums);
    k_scan2<<<1, 128, 0, stream>>>(bsums, boff);
    k_scan3<<<(N_NODES + 255) / 256, 256, 0, stream>>>(offs, boff, cursor);
    k_fill<<<(N_EDGES + 255) / 256, 256, 0, stream>>>(src, dst, cursor, ssrc);

    k_layer1<<<512, 256, 0, stream>>>(node_x, ssrc, offs, deg, W1l, W1r, b1, h1);
    k_layer2<<<512, 256, 0, stream>>>(h1, ssrc, offs, deg, batch, W2l, W2r, b2, gsum, gcnt);
    k_final<<<N_GRAPHS, 128, 0, stream>>>(bert, Wad, bad, Wm, bm, gsum, gcnt, out);
}

// Round 3
// 364.961 us; speedup vs baseline: 1.6361x; 1.6361x over previous
//
#include <hip/hip_runtime.h>

#define N_NODES 100000
#define N_EDGES 600000
#define N_GRAPHS 64

// ---------------- CSR build ----------------

__global__ void k_count(const int* __restrict__ dst, int* __restrict__ deg) {
    int e = blockIdx.x * 256 + threadIdx.x;
    if (e < N_EDGES) atomicAdd(&deg[dst[e]], 1);
}

__global__ void k_scan1(const int* __restrict__ deg, int* __restrict__ offs,
                        int* __restrict__ bsums) {
    __shared__ int s[256];
    int t = threadIdx.x, b = blockIdx.x;
    int base = b * 1024 + t * 4;
    int v0 = (base + 0 < N_NODES) ? deg[base + 0] : 0;
    int v1 = (base + 1 < N_NODES) ? deg[base + 1] : 0;
    int v2 = (base + 2 < N_NODES) ? deg[base + 2] : 0;
    int v3 = (base + 3 < N_NODES) ? deg[base + 3] : 0;
    int tsum = v0 + v1 + v2 + v3;
    s[t] = tsum;
    __syncthreads();
    for (int o = 1; o < 256; o <<= 1) {
        int x = (t >= o) ? s[t - o] : 0;
        __syncthreads();
        s[t] += x;
        __syncthreads();
    }
    int p = s[t] - tsum;
    if (base + 0 < N_NODES) offs[base + 0] = p;
    p += v0;
    if (base + 1 < N_NODES) offs[base + 1] = p;
    p += v1;
    if (base + 2 < N_NODES) offs[base + 2] = p;
    p += v2;
    if (base + 3 < N_NODES) offs[base + 3] = p;
    if (t == 255) bsums[b] = s[255];
}

__global__ void k_scan2(const int* __restrict__ bsums, int* __restrict__ boff) {
    __shared__ int s[128];
    int t = threadIdx.x;
    int nb = (N_NODES + 1023) / 1024;
    int v = (t < nb) ? bsums[t] : 0;
    s[t] = v;
    __syncthreads();
    for (int o = 1; o < 128; o <<= 1) {
        int x = (t >= o) ? s[t - o] : 0;
        __syncthreads();
        s[t] += x;
        __syncthreads();
    }
    boff[t] = s[t] - v;
}

__global__ void k_scan3(int* __restrict__ offs, const int* __restrict__ boff,
                        int* __restrict__ cursor) {
    int i = blockIdx.x * 256 + threadIdx.x;
    if (i < N_NODES) {
        int v = offs[i] + boff[i >> 10];
        offs[i] = v;
        cursor[i] = v;
    }
}

__global__ void k_fill(const int* __restrict__ src, const int* __restrict__ dst,
                       int* __restrict__ cursor, int* __restrict__ ssrc) {
    int e = blockIdx.x * 256 + threadIdx.x;
    if (e < N_EDGES) {
        int d = dst[e];
        int pos = atomicAdd(&cursor[d], 1);
        ssrc[pos] = src[e];
    }
}

// pack W1 into float2 [k*64+d] = (W1l[d][k], W1r[d][k]) so the transform's
// per-k read is one contiguous 512B line per wave (L2 broadcast across waves)
__global__ void k_prepack(const float* __restrict__ W1l, const float* __restrict__ W1r,
                          float2* __restrict__ Wc) {
    int i = blockIdx.x * 256 + threadIdx.x;
    if (i < 128 * 64) {
        int k = i >> 6, d = i & 63;
        Wc[i] = make_float2(W1l[d * 128 + k], W1r[d * 128 + k]);
    }
}

// ---------------- SAGE layer 1 (fused gather + transform + relu) ----------------
// 4-wide unrolled gather w/ scalar neighbor indices; 8-node groups; W from global L2.

__launch_bounds__(256)
__global__ void k_layer1(const float* __restrict__ x, const int* __restrict__ ssrc,
                         const int* __restrict__ offs, const int* __restrict__ deg,
                         const float2* __restrict__ Wc, const float* __restrict__ b1,
                         float* __restrict__ h1) {
    __shared__ float2 S[4][8][128];  // 32 KB: (mean_k, x_k) for 8 nodes per wave
    int tid = threadIdx.x, wave = tid >> 6, lane = tid & 63;
    float bias = b1[lane];
    const float2* x2 = (const float2*)x;
    int gw = blockIdx.x * 4 + wave;
    int nw = gridDim.x * 4;

    // N_NODES % 8 == 0 and the stride keeps groups aligned -> all groups full.
    for (int base = gw * 8; base < N_NODES; base += nw * 8) {
#pragma unroll 1
        for (int j = 0; j < 8; ++j) {
            int node = base + j;
            int o  = __builtin_amdgcn_readfirstlane(offs[node]);
            int dg = __builtin_amdgcn_readfirstlane(deg[node]);
            float ax0 = 0.f, ay0 = 0.f, ax1 = 0.f, ay1 = 0.f;
            float ax2 = 0.f, ay2 = 0.f, ax3 = 0.f, ay3 = 0.f;
            int last = dg - 1;
            for (int u = 0; u < dg; u += 4) {
                int n0 = ssrc[o + u];
                int n1 = ssrc[o + min(u + 1, last)];
                int n2 = ssrc[o + min(u + 2, last)];
                int n3 = ssrc[o + min(u + 3, last)];
                float2 v0 = x2[n0 * 64 + lane];
                float2 v1 = x2[n1 * 64 + lane];
                float2 v2 = x2[n2 * 64 + lane];
                float2 v3 = x2[n3 * 64 + lane];
                float m1 = (u + 1 < dg) ? 1.f : 0.f;
                float m2 = (u + 2 < dg) ? 1.f : 0.f;
                float m3 = (u + 3 < dg) ? 1.f : 0.f;
                ax0 += v0.x;               ay0 += v0.y;
                ax1 = fmaf(v1.x, m1, ax1); ay1 = fmaf(v1.y, m1, ay1);
                ax2 = fmaf(v2.x, m2, ax2); ay2 = fmaf(v2.y, m2, ay2);
                ax3 = fmaf(v3.x, m3, ax3); ay3 = fmaf(v3.y, m3, ay3);
            }
            float inv = 1.f / (float)max(dg, 1);
            float ax = (ax0 + ax1) + (ax2 + ax3);
            float ay = (ay0 + ay1) + (ay2 + ay3);
            float2 xi = x2[node * 64 + lane];
            S[wave][j][2 * lane]     = make_float2(ax * inv, xi.x);
            S[wave][j][2 * lane + 1] = make_float2(ay * inv, xi.y);
        }
        float a0 = bias, a1 = bias, a2 = bias, a3 = bias;
        float a4 = bias, a5 = bias, a6 = bias, a7 = bias;
#pragma unroll 4
        for (int k = 0; k < 128; ++k) {
            float2 w = Wc[k * 64 + lane];  // global, L2-broadcast
            float2 s0 = S[wave][0][k]; a0 += w.x * s0.x + w.y * s0.y;
            float2 s1 = S[wave][1][k]; a1 += w.x * s1.x + w.y * s1.y;
            float2 s2 = S[wave][2][k]; a2 += w.x * s2.x + w.y * s2.y;
            float2 s3 = S[wave][3][k]; a3 += w.x * s3.x + w.y * s3.y;
            float2 s4 = S[wave][4][k]; a4 += w.x * s4.x + w.y * s4.y;
            float2 s5 = S[wave][5][k]; a5 += w.x * s5.x + w.y * s5.y;
            float2 s6 = S[wave][6][k]; a6 += w.x * s6.x + w.y * s6.y;
            float2 s7 = S[wave][7][k]; a7 += w.x * s7.x + w.y * s7.y;
        }
        h1[(base + 0) * 64 + lane] = fmaxf(a0, 0.f);
        h1[(base + 1) * 64 + lane] = fmaxf(a1, 0.f);
        h1[(base + 2) * 64 + lane] = fmaxf(a2, 0.f);
        h1[(base + 3) * 64 + lane] = fmaxf(a3, 0.f);
        h1[(base + 4) * 64 + lane] = fmaxf(a4, 0.f);
        h1[(base + 5) * 64 + lane] = fmaxf(a5, 0.f);
        h1[(base + 6) * 64 + lane] = fmaxf(a6, 0.f);
        h1[(base + 7) * 64 + lane] = fmaxf(a7, 0.f);
    }
}

// ---------------- SAGE layer 2 (fused gather + transform + pooling) ----------------

__launch_bounds__(256)
__global__ void k_layer2(const float* __restrict__ h1, const int* __restrict__ ssrc,
                         const int* __restrict__ offs, const int* __restrict__ deg,
                         const int* __restrict__ batch,
                         const float* __restrict__ W2l, const float* __restrict__ W2r,
                         const float* __restrict__ b2,
                         float* __restrict__ gsum, float* __restrict__ gcnt) {
    __shared__ float2 Wc[64 * 16];        // 8 KB
    __shared__ float2 S[4][8][64];        // 16 KB: (mean_k, h1_k) for 8 nodes/wave
    __shared__ float bins[N_GRAPHS][17];  // 4.25 KB
    int tid = threadIdx.x;
    for (int i = tid; i < 64 * 16; i += 256) {
        int k = i >> 4, d = i & 15;
        Wc[i] = make_float2(W2l[d * 64 + k], W2r[d * 64 + k]);
    }
    for (int i = tid; i < N_GRAPHS * 17; i += 256) ((float*)bins)[i] = 0.f;
    __syncthreads();

    int wave = tid >> 6, lane = tid & 63;
    int d = lane & 15, jq = lane >> 4;
    float bias = b2[d];

    int chunk = (N_NODES + gridDim.x - 1) / gridDim.x;
    int cs = blockIdx.x * chunk;
    int ce = min(N_NODES, cs + chunk);

    for (int base = cs + wave * 8; base < ce; base += 32) {
        int cnt = min(8, ce - base);
        for (int j = 0; j < cnt; ++j) {
            int node = base + j;
            int o  = __builtin_amdgcn_readfirstlane(offs[node]);
            int dg = __builtin_amdgcn_readfirstlane(deg[node]);
            float a0 = 0.f, a1 = 0.f, a2 = 0.f, a3 = 0.f;
            int last = dg - 1;
            for (int u = 0; u < dg; u += 4) {
                int n0 = ssrc[o + u];
                int n1 = ssrc[o + min(u + 1, last)];
                int n2 = ssrc[o + min(u + 2, last)];
                int n3 = ssrc[o + min(u + 3, last)];
                float v0 = h1[n0 * 64 + lane];
                float v1 = h1[n1 * 64 + lane];
                float v2 = h1[n2 * 64 + lane];
                float v3 = h1[n3 * 64 + lane];
                float m1 = (u + 1 < dg) ? 1.f : 0.f;
                float m2 = (u + 2 < dg) ? 1.f : 0.f;
                float m3 = (u + 3 < dg) ? 1.f : 0.f;
                a0 += v0;
                a1 = fmaf(v1, m1, a1);
                a2 = fmaf(v2, m2, a2);
                a3 = fmaf(v3, m3, a3);
            }
            float inv = 1.f / (float)max(dg, 1);
            S[wave][j][lane] = make_float2(((a0 + a1) + (a2 + a3)) * inv,
                                           h1[node * 64 + lane]);
        }
#pragma unroll
        for (int p = 0; p < 2; ++p) {
            int j = p * 4 + jq;
            float a = bias;
#pragma unroll 8
            for (int k = 0; k < 64; ++k) {
                float2 w = Wc[k * 16 + d];
                float2 s = S[wave][j][k];
                a += w.x * s.x + w.y * s.y;
            }
            if (j < cnt) {
                int g = batch[base + j];
                atomicAdd(&bins[g][d], a);
                if (d == 0) atomicAdd(&bins[g][16], 1.f);
            }
        }
    }
    __syncthreads();
    for (int i = tid; i < N_GRAPHS * 17; i += 256) {
        int g = i / 17, c = i - g * 17;
        float v = bins[g][c];
        if (v != 0.f) {
            if (c < 16) atomicAdd(&gsum[g * 16 + c], v);
            else        atomicAdd(&gcnt[g], v);
        }
    }
}

// ---------------- final: BERT head + graph head, concat ----------------

__global__ void k_final(const float* __restrict__ bert, const float* __restrict__ Wad,
                        const float* __restrict__ bad, const float* __restrict__ Wm,
                        const float* __restrict__ bm, const float* __restrict__ gsum,
                        const float* __restrict__ gcnt, float* __restrict__ out) {
    int g = blockIdx.x;
    int t = threadIdx.x;
    if (t < 64) {
        const float4* br = (const float4*)(bert + g * 768);
        const float4* wr = (const float4*)(Wad + t * 768);
        float acc = bad[t];
#pragma unroll 8
        for (int k = 0; k < 192; ++k) {
            float4 bv = br[k], wv = wr[k];
            acc += bv.x * wv.x + bv.y * wv.y + bv.z * wv.z + bv.w * wv.w;
        }
        out[g * 80 + t] = acc;
    } else if (t < 80) {
        int j = t - 64;
        float ic = 1.f / fmaxf(gcnt[g], 1.f);
        float acc = bm[j];
#pragma unroll
        for (int k = 0; k < 16; ++k) acc += Wm[j * 16 + k] * gsum[g * 16 + k] * ic;
        out[g * 80 + t] = acc;
    }
}

extern "C" void kernel_launch(void* const* d_in, const int* in_sizes, int n_in,
                              void* d_out, int out_size, void* d_ws, size_t ws_size,
                              hipStream_t stream) {
    const float* bert   = (const float*)d_in[0];
    const float* node_x = (const float*)d_in[1];
    const int*   edge   = (const int*)d_in[2];
    const int*   batch  = (const int*)d_in[3];
    const float* Wad    = (const float*)d_in[4];
    const float* bad    = (const float*)d_in[5];
    const float* W1l    = (const float*)d_in[6];
    const float* W1r    = (const float*)d_in[7];
    const float* b1     = (const float*)d_in[8];
    const float* W2l    = (const float*)d_in[9];
    const float* W2r    = (const float*)d_in[10];
    const float* b2     = (const float*)d_in[11];
    const float* Wm     = (const float*)d_in[12];
    const float* bm     = (const float*)d_in[13];
    float* out = (float*)d_out;

    const int* src = edge;
    const int* dst = edge + N_EDGES;

    char* ws = (char*)d_ws;
    int*    deg    = (int*)(ws);                    //   400,000 B
    int*    offs   = (int*)(ws + 400000);           //   400,000 B
    int*    cursor = (int*)(ws + 800000);           //   400,000 B
    int*    bsums  = (int*)(ws + 1200000);          //       512 B
    int*    boff   = (int*)(ws + 1200512);          //       512 B
    int*    ssrc   = (int*)(ws + 1201024);          // 2,400,000 B
    float*  h1     = (float*)(ws + 3601024);        // 25,600,000 B
    float2* Wc1    = (float2*)(ws + 29201024);      //    65,536 B
    float*  gsum   = (float*)(ws + 29266560);       //     4,096 B
    float*  gcnt   = (float*)(ws + 29270656);       //       256 B
    // total ~29.3 MB

    hipMemsetAsync(deg, 0, 400000, stream);
    hipMemsetAsync(gsum, 0, 4096 + 256, stream);

    k_count<<<(N_EDGES + 255) / 256, 256, 0, stream>>>(dst, deg);
    k_scan1<<<(N_NODES + 1023) / 1024, 256, 0, stream>>>(deg, offs, bsums);
    k_scan2<<<1, 128, 0, stream>>>(bsums, boff);
    k_scan3<<<(N_NODES + 255) / 256, 256, 0, stream>>>(offs, boff, cursor);
    k_fill<<<(N_EDGES + 255) / 256, 256, 0, stream>>>(src, dst, cursor, ssrc);
    k_prepack<<<32, 256, 0, stream>>>(W1l, W1r, Wc1);

    k_layer1<<<1024, 256, 0, stream>>>(node_x, ssrc, offs, deg, Wc1, b1, h1);
    k_layer2<<<1024, 256, 0, stream>>>(h1, ssrc, offs, deg, batch, W2l, W2r, b2, gsum, gcnt);
    k_final<<<N_GRAPHS, 128, 0, stream>>>(bert, Wad, bad, Wm, bm, gsum, gcnt, out);
}